// Round 10
// baseline (290.452 us; speedup 1.0000x reference)
//
#include <hip/hip_runtime.h>
#include <cstdint>

#define NN 100000
#define CH 128
#define NT_BLK 32
#define SCAN_B 256

typedef __bf16 bf16x8 __attribute__((ext_vector_type(8)));
typedef __bf16 bf16x4 __attribute__((ext_vector_type(4)));
typedef float  f32x4  __attribute__((ext_vector_type(4)));

__device__ __forceinline__ float b2f(unsigned short u) {
    union { unsigned int i; float f; } v; v.i = ((unsigned int)u) << 16; return v.f;
}

// accumulate 8 bf16 channels (packed in uint4) into f32 sums with mask m
__device__ __forceinline__ void acc8(float* s, const uint4& v, float m) {
    const unsigned d[4] = {v.x, v.y, v.z, v.w};
#pragma unroll
    for (int j = 0; j < 4; ++j) {
        union { unsigned i; float f; } lo, hi;
        lo.i = d[j] << 16;
        hi.i = d[j] & 0xffff0000u;
        s[2 * j]     = fmaf(m, lo.f, s[2 * j]);
        s[2 * j + 1] = fmaf(m, hi.f, s[2 * j + 1]);
    }
}

// ================= init: zero cnt | x->bf16 | weights->fragments (independent) ===
__global__ __launch_bounds__(256) void k_init(
    const float* __restrict__ x, unsigned short* __restrict__ xb,
    const float* __restrict__ W1l, const float* __restrict__ W1r,
    const float* __restrict__ W2l, const float* __restrict__ W2r,
    __bf16* __restrict__ wB, int* __restrict__ cnt)
{
    const int gtid = blockIdx.x * 256 + threadIdx.x;
    const int gsz = gridDim.x * 256;
    for (int i = gtid; i < NN; i += gsz) cnt[i] = 0;
    for (int i = gtid; i < NN * CH / 8; i += gsz) {
        const float4 a = *reinterpret_cast<const float4*>(x + (size_t)i * 8);
        const float4 c = *reinterpret_cast<const float4*>(x + (size_t)i * 8 + 4);
        bf16x8 o;
        o[0] = (__bf16)a.x; o[1] = (__bf16)a.y; o[2] = (__bf16)a.z; o[3] = (__bf16)a.w;
        o[4] = (__bf16)c.x; o[5] = (__bf16)c.y; o[6] = (__bf16)c.z; o[7] = (__bf16)c.w;
        *reinterpret_cast<bf16x8*>(xb + (size_t)i * 8) = o;
    }
    if (gtid < 8192) {
        // [layer][kt:8][nt:8][lane:64][8]: elem i = B[kt*32+(lane>>4)*8+i][nt*16+(lane&15)]
        const int l    = gtid >> 12;
        const int rem  = gtid & 4095;
        const int kt   = rem >> 9;
        const int nt   = (rem >> 6) & 7;
        const int lane = rem & 63;
        const float* Wl = l ? W2l : W1l;
        const float* Wr = l ? W2r : W1r;
        const int nn = nt * 16 + (lane & 15);
        const int k0 = kt * 32 + (lane >> 4) * 8;
        bf16x8 v;
#pragma unroll
        for (int i = 0; i < 8; ++i) {
            const int k = k0 + i;
            const float f = (k < CH) ? Wl[k * CH + nn] : Wr[(k - CH) * CH + nn];
            v[i] = (__bf16)f;
        }
        *reinterpret_cast<bf16x8*>(wB + (size_t)gtid * 8) = v;
    }
}

// ================= count + per-edge slot (rank among same-dst edges) =================
__global__ void k_count(const int* __restrict__ dst, int* __restrict__ cnt,
                        int* __restrict__ slot, int E) {
    const int e = blockIdx.x * blockDim.x + threadIdx.x;
    if (e < E) slot[e] = atomicAdd(&cnt[dst[e]], 1);
}

// ================= per-chunk exclusive scan -> rowptr, totals -> bsum =================
__global__ void k_scan(const int* __restrict__ cnt, int* __restrict__ rowptr,
                       int* __restrict__ bsum, int n) {
    __shared__ int tmp[SCAN_B];
    const int t = threadIdx.x;
    const int i = blockIdx.x * SCAN_B + t;
    const int v = (i < n) ? cnt[i] : 0;
    tmp[t] = v;
    __syncthreads();
    for (int off = 1; off < SCAN_B; off <<= 1) {
        const int tv = (t >= off) ? tmp[t - off] : 0;
        __syncthreads();
        tmp[t] += tv;
        __syncthreads();
    }
    if (i < n) rowptr[i] = tmp[t] - v;
    if (t == SCAN_B - 1) bsum[blockIdx.x] = tmp[SCAN_B - 1];
}

// ================= add chunk-prefix (<=391 totals: <=2 loads/thread) =================
__global__ void k_add(int* __restrict__ rowptr, const int* __restrict__ bsum, int n, int E) {
    __shared__ int sd[SCAN_B];
    const int t = threadIdx.x;
    int s = 0;
    for (int j = t; j < (int)blockIdx.x; j += SCAN_B) s += bsum[j];
    sd[t] = s;
    __syncthreads();
    for (int off = SCAN_B / 2; off > 0; off >>= 1) {
        if (t < off) sd[t] += sd[t + off];
        __syncthreads();
    }
    const int base = sd[0];
    const int i = blockIdx.x * SCAN_B + t;
    if (i < n) rowptr[i] += base;
    if (i == 0) rowptr[n] = E;
}

// ================= CSR fill — atomic-free (uses precomputed slot) =================
__global__ void k_fill(const int* __restrict__ src, const int* __restrict__ dst,
                       const int* __restrict__ slot, const int* __restrict__ rowptr,
                       int* __restrict__ csr, int E) {
    const int e = blockIdx.x * blockDim.x + threadIdx.x;
    if (e < E) csr[rowptr[dst[e]] + slot[e]] = src[e];
}

// ================= fused SAGE layer (MFMA) =================
// Phase 1 (NEW): wave-per-node gather. Wave w owns nodes w*8..+7 (seq).
// Lanes: sub=lane>>4 picks 1 of 4 parallel neighbor rows, cl=lane&15 picks an
// 8-channel slice read as one uint4 (16 B — G13 sweet spot). Batch = 4 rows =
// 1 KB/issue; unroll-2 keeps 8 rows (2 KB) in flight; B-batch gated by a
// WAVE-UNIFORM branch (deg<=4 skips it). Channel sums complete via 2 shfl_xor
// rounds (16,32). Node index is wave-uniform -> rowptr loads scalarize; the
// 8-node loop is fully unrolled so all s_loads hoist.
// LDS layout + XOR swizzle + Phase 2 + epilogue: byte-identical to R9.
template<bool FC>
__global__ __launch_bounds__(256) void k_layer(
    const unsigned short* __restrict__ feat,
    const int* __restrict__ rowptr, const int* __restrict__ csr,
    const bf16x8* __restrict__ wfrag,
    const float* __restrict__ bias,
    const float* __restrict__ Wfc, const float* __restrict__ bfc,
    void* __restrict__ outv)
{
    __shared__ unsigned short a_lds[NT_BLK * 256];   // 16 KB
    __shared__ float red[4][16];
    char* lb = (char*)a_lds;
    const int tid = threadIdx.x;
    const int node0 = blockIdx.x * NT_BLK;
    const int lane = tid & 63;
    const int w = tid >> 6;
    const int sub = lane >> 4;       // neighbor-row slot 0..3
    const int cl  = lane & 15;       // 8-channel slice

    // ---- Phase 1: gather-mean, wave-per-node ----
#pragma unroll
    for (int i = 0; i < 8; ++i) {
        const int r = w * 8 + i;               // local row 0..31
        const int node = node0 + r;            // NN % 32 == 0: always valid
        const int swz = (r & 7) << 4;
        const int r0 = rowptr[node], r1 = rowptr[node + 1];
        const int last = r1 - 1;
        float s[8] = {0.f, 0.f, 0.f, 0.f, 0.f, 0.f, 0.f, 0.f};

        for (int rr = r0; rr < r1; rr += 8) {
            const int pA = rr + sub;
            const int iA = csr[pA <= last ? pA : last];
            const uint4 va = *reinterpret_cast<const uint4*>(feat + (size_t)iA * CH + cl * 8);
            const float mA = (pA < r1) ? 1.f : 0.f;
            if (rr + 4 < r1) {                 // wave-uniform: skip B batch for deg<=4
                const int pB = rr + 4 + sub;
                const int iB = csr[pB <= last ? pB : last];
                const uint4 vb = *reinterpret_cast<const uint4*>(feat + (size_t)iB * CH + cl * 8);
                const float mB = (pB < r1) ? 1.f : 0.f;
                acc8(s, va, mA);
                acc8(s, vb, mB);
            } else {
                acc8(s, va, mA);
            }
        }

        // combine the 4 sub-row partials: lanes l, l^16, l^32, l^48
#pragma unroll
        for (int j = 0; j < 8; ++j) {
            s[j] += __shfl_xor(s[j], 16);
            s[j] += __shfl_xor(s[j], 32);
        }

        const float invd = 1.0f / fmaxf((float)(r1 - r0), 1.0f);
        if (sub == 0) {
            bf16x8 o;
#pragma unroll
            for (int j = 0; j < 8; ++j) o[j] = (__bf16)(s[j] * invd);
            *reinterpret_cast<bf16x8*>(lb + r * 512 + ((cl * 16) ^ swz)) = o;
        } else if (sub == 1) {
            const uint4 u = *reinterpret_cast<const uint4*>(feat + (size_t)node * CH + cl * 8);
            *reinterpret_cast<uint4*>(lb + r * 512 + ((256 + cl * 16) ^ swz)) = u;   // exact bit copy
        }
    }
    __syncthreads();

    // ---- Phase 2: MFMA dual-GEMM (K=256 folded) — unchanged ----
    const int rows16 = (w >> 1) * 16;
    const int ntbase = (w & 1) * 4;
    const int row = rows16 + (lane & 15);
    const int rswz = (row & 7) << 4;
    const int abase = row * 512;
    const int asub = (lane >> 4) * 16;

    f32x4 acc[4];
#pragma unroll
    for (int nt = 0; nt < 4; ++nt) { acc[nt][0] = 0.f; acc[nt][1] = 0.f; acc[nt][2] = 0.f; acc[nt][3] = 0.f; }

#pragma unroll
    for (int kt = 0; kt < 8; ++kt) {
        const bf16x8 a = *reinterpret_cast<const bf16x8*>(lb + abase + ((kt * 64 + asub) ^ rswz));
        const bf16x8* bp = wfrag + kt * 512 + ntbase * 64 + lane;
#pragma unroll
        for (int nt = 0; nt < 4; ++nt) {
            const bf16x8 b = bp[nt * 64];
            acc[nt] = __builtin_amdgcn_mfma_f32_16x16x32_bf16(a, b, acc[nt], 0, 0, 0);
        }
    }

    // ---- Epilogue — unchanged ----
    const int nbase = lane & 15;
    if (!FC) {
        __bf16* out = (__bf16*)outv;
#pragma unroll
        for (int nt = 0; nt < 4; ++nt) {
            const int ch = (ntbase + nt) * 16 + nbase;
            const float bv = bias[ch];
#pragma unroll
            for (int rr = 0; rr < 4; ++rr) {
                const int node = node0 + rows16 + (lane >> 4) * 4 + rr;
                if (node < NN)
                    out[(size_t)node * CH + ch] = (__bf16)fmaxf(acc[nt][rr] + bv, 0.0f);
            }
        }
    } else {
        float* out = (float*)outv;
        float p[4] = {0.f, 0.f, 0.f, 0.f};
#pragma unroll
        for (int nt = 0; nt < 4; ++nt) {
            const int ch = (ntbase + nt) * 16 + nbase;
            const float bv = bias[ch];
            const float wf = Wfc[ch];
#pragma unroll
            for (int rr = 0; rr < 4; ++rr)
                p[rr] += fmaxf(acc[nt][rr] + bv, 0.0f) * wf;
        }
#pragma unroll
        for (int m = 1; m < 16; m <<= 1) {
#pragma unroll
            for (int rr = 0; rr < 4; ++rr) p[rr] += __shfl_xor(p[rr], m);
        }
        if (nbase == 0) {
#pragma unroll
            for (int rr = 0; rr < 4; ++rr)
                red[w][(lane >> 4) * 4 + rr] = p[rr];
        }
        __syncthreads();
        if (tid < NT_BLK) {
            const int rloc = tid;
            const float z = (rloc < 16 ? red[0][rloc] + red[1][rloc]
                                       : red[2][rloc - 16] + red[3][rloc - 16]) + bfc[0];
            const int node = node0 + rloc;
            if (node < NN) out[node] = 1.0f / (1.0f + expf(-z));
        }
    }
}

// ================= launch =================

extern "C" void kernel_launch(void* const* d_in, const int* in_sizes, int n_in,
                              void* d_out, int out_size, void* d_ws, size_t ws_size,
                              hipStream_t stream) {
    const float* x   = (const float*)d_in[0];
    const int*   ei  = (const int*)d_in[1];
    const float* W1l = (const float*)d_in[2];
    const float* W1r = (const float*)d_in[3];
    const float* b1  = (const float*)d_in[4];
    const float* W2l = (const float*)d_in[5];
    const float* W2r = (const float*)d_in[6];
    const float* b2  = (const float*)d_in[7];
    const float* Wfc = (const float*)d_in[8];
    const float* bfc = (const float*)d_in[9];

    const int E = in_sizes[1] / 2;
    const int* src = ei;
    const int* dst = ei + E;

    // ws: h1 [NN*CH bf16] | xb [NN*CH bf16] | wB [65536 bf16] | cnt | rowptr | bsum | slot | csr
    unsigned short* h1 = (unsigned short*)d_ws;
    unsigned short* xb = h1 + (size_t)NN * CH;
    __bf16* wB     = (__bf16*)(xb + (size_t)NN * CH);
    int*    cnt    = (int*)(wB + 65536);
    int*    rowptr = cnt + NN;
    int*    bsum   = rowptr + NN + 1;
    int*    slot   = bsum + 512;
    int*    csr    = slot + E;

    const int nb = (NN + SCAN_B - 1) / SCAN_B;      // 391
    const int eb = (E + 255) / 256;                 // 2500

    k_init<<<2048, 256, 0, stream>>>(x, xb, W1l, W1r, W2l, W2r, wB, cnt);
    k_count<<<eb, 256, 0, stream>>>(dst, cnt, slot, E);
    k_scan<<<nb, SCAN_B, 0, stream>>>(cnt, rowptr, bsum, NN);
    k_add<<<nb, SCAN_B, 0, stream>>>(rowptr, bsum, NN, E);
    k_fill<<<eb, 256, 0, stream>>>(src, dst, slot, rowptr, csr, E);

    const int blocks = (NN + NT_BLK - 1) / NT_BLK;   // 3125
    k_layer<false><<<blocks, 256, 0, stream>>>(
        xb, rowptr, csr, (const bf16x8*)wB, b1, Wfc, bfc, h1);
    k_layer<true><<<blocks, 256, 0, stream>>>(
        h1, rowptr, csr, (const bf16x8*)(wB + 32768), b2, Wfc, bfc, d_out);
}

// Round 13
// 257.399 us; speedup vs baseline: 1.1284x; 1.1284x over previous
//
#include <hip/hip_runtime.h>
#include <cstdint>

#define NN 100000
#define CH 128
#define NT_BLK 32
#define SCAN_B 256

#define AGG_F (1u << 30)
#define PRE_F (2u << 30)
#define VAL_M ((1u << 30) - 1)

typedef __bf16 bf16x8 __attribute__((ext_vector_type(8)));
typedef __bf16 bf16x4 __attribute__((ext_vector_type(4)));
typedef float  f32x4  __attribute__((ext_vector_type(4)));

__device__ __forceinline__ float b2f(unsigned short u) {
    union { unsigned int i; float f; } v; v.i = ((unsigned int)u) << 16; return v.f;
}

// ====== fused: edge count+slot | x->bf16 | weights->fragments (independent) ======
// blocks [0,eb): slot[e]=cnt[dst[e]]++ ; [eb,eb+xcb): xconv ; [eb+xcb,+32): wconv.
// cnt pre-zeroed by memsetAsync. xconv BW work fills CUs during count's atomic latency.
__global__ __launch_bounds__(256) void k_count_xw(
    const int* __restrict__ dst, int* __restrict__ cnt, int* __restrict__ slot, int E,
    const float* __restrict__ x, unsigned short* __restrict__ xb,
    const float* __restrict__ W1l, const float* __restrict__ W1r,
    const float* __restrict__ W2l, const float* __restrict__ W2r,
    __bf16* __restrict__ wB, int eb, int xcb)
{
    const int b = blockIdx.x;
    const int t = threadIdx.x;
    if (b < eb) {
        const int e = b * 256 + t;
        if (e < E) slot[e] = atomicAdd(&cnt[dst[e]], 1);
        return;
    }
    if (b < eb + xcb) {
        const size_t i = ((size_t)(b - eb) * 256 + t) * 8;
        if (i < (size_t)NN * CH) {
            const float4 a = *reinterpret_cast<const float4*>(x + i);
            const float4 c = *reinterpret_cast<const float4*>(x + i + 4);
            bf16x8 o;
            o[0] = (__bf16)a.x; o[1] = (__bf16)a.y; o[2] = (__bf16)a.z; o[3] = (__bf16)a.w;
            o[4] = (__bf16)c.x; o[5] = (__bf16)c.y; o[6] = (__bf16)c.z; o[7] = (__bf16)c.w;
            *reinterpret_cast<bf16x8*>(xb + i) = o;
        }
        return;
    }
    // weight fragments: [layer][kt:8][nt:8][lane:64][8]:
    //   elem i = B[kt*32+(lane>>4)*8+i][nt*16+(lane&15)], B=[Wl;Wr] (256x128)
    const int gtid = (b - eb - xcb) * 256 + t;   // 0..8191
    const int l    = gtid >> 12;
    const int rem  = gtid & 4095;
    const int kt   = rem >> 9;
    const int nt   = (rem >> 6) & 7;
    const int lane = rem & 63;
    const float* Wl = l ? W2l : W1l;
    const float* Wr = l ? W2r : W1r;
    const int nn = nt * 16 + (lane & 15);
    const int k0 = kt * 32 + (lane >> 4) * 8;
    bf16x8 v;
#pragma unroll
    for (int i = 0; i < 8; ++i) {
        const int k = k0 + i;
        const float f = (k < CH) ? Wl[k * CH + nn] : Wr[(k - CH) * CH + nn];
        v[i] = (__bf16)f;
    }
    *reinterpret_cast<bf16x8*>(wB + (size_t)gtid * 8) = v;
}

// ====== single-pass scan, decoupled lookback (flags pre-zeroed by memset) ======
// 391 blocks x 4 waves — all co-resident (<< 8192-wave capacity), no deadlock.
// Wave 0 does a 64-wide lookback window; worst case ceil(391/64)=7 steps.
__global__ __launch_bounds__(SCAN_B) void k_scan_lb(
    const int* __restrict__ cnt, int* __restrict__ rowptr,
    unsigned* __restrict__ flagval, int n, int E)
{
    __shared__ int tmp[SCAN_B];
    __shared__ int sbase;
    const int t = threadIdx.x;
    const int c = blockIdx.x;
    const int i = c * SCAN_B + t;
    const int v = (i < n) ? cnt[i] : 0;
    tmp[t] = v;
    __syncthreads();
    for (int off = 1; off < SCAN_B; off <<= 1) {
        const int tv = (t >= off) ? tmp[t - off] : 0;
        __syncthreads();
        tmp[t] += tv;
        __syncthreads();
    }
    const int total = tmp[SCAN_B - 1];

    if (c == 0) {
        if (t == 0) {
            sbase = 0;
            __hip_atomic_store(&flagval[0], PRE_F | (unsigned)total,
                               __ATOMIC_RELEASE, __HIP_MEMORY_SCOPE_AGENT);
        }
    } else {
        if (t == 0)
            __hip_atomic_store(&flagval[c], AGG_F | (unsigned)total,
                               __ATOMIC_RELEASE, __HIP_MEMORY_SCOPE_AGENT);
        if (t < 64) {
            int base = 0;
            int j = c - 1;
            while (true) {
                const int idx = j - t;
                unsigned fv = 0;
                if (idx >= 0) {
                    do {
                        fv = __hip_atomic_load(&flagval[idx], __ATOMIC_ACQUIRE,
                                               __HIP_MEMORY_SCOPE_AGENT);
                    } while ((fv >> 30) == 0);
                }
                const unsigned long long pmask = __ballot(idx >= 0 && (fv >> 30) == 2);
                if (pmask) {
                    const int firstPre = __ffsll(pmask) - 1;   // smallest lane = largest idx
                    int contrib = (t <= firstPre && idx >= 0) ? (int)(fv & VAL_M) : 0;
#pragma unroll
                    for (int m = 1; m < 64; m <<= 1) contrib += __shfl_xor(contrib, m);
                    base += contrib;
                    break;
                }
                int contrib = (idx >= 0) ? (int)(fv & VAL_M) : 0;
#pragma unroll
                for (int m = 1; m < 64; m <<= 1) contrib += __shfl_xor(contrib, m);
                base += contrib;
                j -= 64;
            }
            if (t == 0) {
                __hip_atomic_store(&flagval[c], PRE_F | (unsigned)(base + total),
                                   __ATOMIC_RELEASE, __HIP_MEMORY_SCOPE_AGENT);
                sbase = base;
            }
        }
    }
    __syncthreads();
    const int base = sbase;
    if (i < n) rowptr[i] = tmp[t] - v + base;   // exclusive + global prefix
    if (i == 0) rowptr[n] = E;
}

// ====== CSR fill — atomic-free (uses precomputed slot) ======
__global__ void k_fill(const int* __restrict__ src, const int* __restrict__ dst,
                       const int* __restrict__ slot, const int* __restrict__ rowptr,
                       int* __restrict__ csr, int E) {
    const int e = blockIdx.x * blockDim.x + threadIdx.x;
    if (e < E) csr[rowptr[dst[e]] + slot[e]] = src[e];
}

// ================= fused SAGE layer (MFMA) — R9 verbatim (known-good) =================
// Phase 1: bf16 gather-mean, group-per-node (8 groups of 32 lanes), MASKED
// unroll-8 (8 ushort4 loads in flight/lane, no serial remainder, no intra-
// iteration sync). bf16 A-tile [32][256] (agg k<128 | skip k>=128), XOR-swizzled.
// Phase 2: wave w -> rows (w>>1)*16..+15, col-half (w&1): 4 nt-tiles, K=256.
// FC=true: fused [128->1] head + sigmoid via 16-lane shfl_xor + LDS combine.
template<bool FC>
__global__ __launch_bounds__(256) void k_layer(
    const unsigned short* __restrict__ feat,
    const int* __restrict__ rowptr, const int* __restrict__ csr,
    const bf16x8* __restrict__ wfrag,
    const float* __restrict__ bias,
    const float* __restrict__ Wfc, const float* __restrict__ bfc,
    void* __restrict__ outv)
{
    __shared__ unsigned short a_lds[NT_BLK * 256];   // 16 KB
    __shared__ float red[4][16];
    char* lb = (char*)a_lds;
    const int tid = threadIdx.x;
    const int node0 = blockIdx.x * NT_BLK;

    const int g = tid >> 5;
    const int q = tid & 31;

#pragma unroll
    for (int it = 0; it < NT_BLK / 8; ++it) {
        const int r = it * 8 + g;
        const int node = node0 + r;
        const int swz = (r & 7) << 4;
        float4 s = make_float4(0.f, 0.f, 0.f, 0.f);
        bf16x4 k2 = {(__bf16)0.f, (__bf16)0.f, (__bf16)0.f, (__bf16)0.f};
        if (node < NN) {
            const int r0 = rowptr[node], r1 = rowptr[node + 1];
            const int last = r1 - 1;
            for (int rr = r0; rr < r1; rr += 8) {
                ushort4 uv[8];
                float mk[8];
#pragma unroll
                for (int u = 0; u < 8; ++u) {
                    const int p = rr + u;
                    const int idx = csr[p <= last ? p : last];
                    uv[u] = *reinterpret_cast<const ushort4*>(feat + (size_t)idx * CH + q * 4);
                    mk[u] = (p < r1) ? 1.f : 0.f;
                }
#pragma unroll
                for (int u = 0; u < 8; ++u) {
                    s.x += mk[u] * b2f(uv[u].x);
                    s.y += mk[u] * b2f(uv[u].y);
                    s.z += mk[u] * b2f(uv[u].z);
                    s.w += mk[u] * b2f(uv[u].w);
                }
            }
            const float invd = 1.0f / fmaxf((float)(r1 - r0), 1.0f);
            s.x *= invd; s.y *= invd; s.z *= invd; s.w *= invd;
            const ushort4 u = *reinterpret_cast<const ushort4*>(feat + (size_t)node * CH + q * 4);
            k2 = *reinterpret_cast<const bf16x4*>(&u);   // exact bit copy
        }
        bf16x4 a;
        a[0] = (__bf16)s.x; a[1] = (__bf16)s.y; a[2] = (__bf16)s.z; a[3] = (__bf16)s.w;
        *reinterpret_cast<bf16x4*>(lb + r * 512 + ((q * 8) ^ swz)) = a;
        *reinterpret_cast<bf16x4*>(lb + r * 512 + ((256 + q * 8) ^ swz)) = k2;
    }
    __syncthreads();

    const int lane = tid & 63;
    const int w = tid >> 6;
    const int rows16 = (w >> 1) * 16;
    const int ntbase = (w & 1) * 4;
    const int row = rows16 + (lane & 15);
    const int rswz = (row & 7) << 4;
    const int abase = row * 512;
    const int asub = (lane >> 4) * 16;

    f32x4 acc[4];
#pragma unroll
    for (int nt = 0; nt < 4; ++nt) { acc[nt][0] = 0.f; acc[nt][1] = 0.f; acc[nt][2] = 0.f; acc[nt][3] = 0.f; }

#pragma unroll
    for (int kt = 0; kt < 8; ++kt) {
        const bf16x8 a = *reinterpret_cast<const bf16x8*>(lb + abase + ((kt * 64 + asub) ^ rswz));
        const bf16x8* bp = wfrag + kt * 512 + ntbase * 64 + lane;
#pragma unroll
        for (int nt = 0; nt < 4; ++nt) {
            const bf16x8 b = bp[nt * 64];
            acc[nt] = __builtin_amdgcn_mfma_f32_16x16x32_bf16(a, b, acc[nt], 0, 0, 0);
        }
    }

    const int nbase = lane & 15;
    if (!FC) {
        __bf16* out = (__bf16*)outv;
#pragma unroll
        for (int nt = 0; nt < 4; ++nt) {
            const int ch = (ntbase + nt) * 16 + nbase;
            const float bv = bias[ch];
#pragma unroll
            for (int rr = 0; rr < 4; ++rr) {
                const int node = node0 + rows16 + (lane >> 4) * 4 + rr;
                if (node < NN)
                    out[(size_t)node * CH + ch] = (__bf16)fmaxf(acc[nt][rr] + bv, 0.0f);
            }
        }
    } else {
        float* out = (float*)outv;
        float p[4] = {0.f, 0.f, 0.f, 0.f};
#pragma unroll
        for (int nt = 0; nt < 4; ++nt) {
            const int ch = (ntbase + nt) * 16 + nbase;
            const float bv = bias[ch];
            const float wf = Wfc[ch];
#pragma unroll
            for (int rr = 0; rr < 4; ++rr)
                p[rr] += fmaxf(acc[nt][rr] + bv, 0.0f) * wf;
        }
#pragma unroll
        for (int m = 1; m < 16; m <<= 1) {
#pragma unroll
            for (int rr = 0; rr < 4; ++rr) p[rr] += __shfl_xor(p[rr], m);
        }
        if (nbase == 0) {
#pragma unroll
            for (int rr = 0; rr < 4; ++rr)
                red[w][(lane >> 4) * 4 + rr] = p[rr];
        }
        __syncthreads();
        if (tid < NT_BLK) {
            const int rloc = tid;
            const float z = (rloc < 16 ? red[0][rloc] + red[1][rloc]
                                       : red[2][rloc - 16] + red[3][rloc - 16]) + bfc[0];
            const int node = node0 + rloc;
            if (node < NN) out[node] = 1.0f / (1.0f + expf(-z));
        }
    }
}

// ================= launch =================

extern "C" void kernel_launch(void* const* d_in, const int* in_sizes, int n_in,
                              void* d_out, int out_size, void* d_ws, size_t ws_size,
                              hipStream_t stream) {
    const float* x   = (const float*)d_in[0];
    const int*   ei  = (const int*)d_in[1];
    const float* W1l = (const float*)d_in[2];
    const float* W1r = (const float*)d_in[3];
    const float* b1  = (const float*)d_in[4];
    const float* W2l = (const float*)d_in[5];
    const float* W2r = (const float*)d_in[6];
    const float* b2  = (const float*)d_in[7];
    const float* Wfc = (const float*)d_in[8];
    const float* bfc = (const float*)d_in[9];

    const int E = in_sizes[1] / 2;
    const int* src = ei;
    const int* dst = ei + E;

    // ws: h1 | xb | wB | cnt[NN] flagval[512] (contiguous: one memset) | rowptr | slot | csr
    unsigned short* h1 = (unsigned short*)d_ws;
    unsigned short* xb = h1 + (size_t)NN * CH;
    __bf16*   wB      = (__bf16*)(xb + (size_t)NN * CH);
    int*      cnt     = (int*)(wB + 65536);
    unsigned* flagval = (unsigned*)(cnt + NN);
    int*      rowptr  = (int*)(flagval + 512);
    int*      slot    = rowptr + NN + 1;
    int*      csr     = slot + E;

    const int nb  = (NN + SCAN_B - 1) / SCAN_B;     // 391
    const int eb  = (E + 255) / 256;                // 2500
    const int xcb = (NN * CH) / 2048;               // 6250

    hipMemsetAsync(cnt, 0, (size_t)(NN + 512) * sizeof(int), stream);  // cnt + flags
    k_count_xw<<<eb + xcb + 32, 256, 0, stream>>>(dst, cnt, slot, E, x, xb,
                                                  W1l, W1r, W2l, W2r, wB, eb, xcb);
    k_scan_lb<<<nb, SCAN_B, 0, stream>>>(cnt, rowptr, flagval, NN, E);
    k_fill<<<eb, 256, 0, stream>>>(src, dst, slot, rowptr, csr, E);

    const int blocks = (NN + NT_BLK - 1) / NT_BLK;   // 3125
    k_layer<false><<<blocks, 256, 0, stream>>>(
        xb, rowptr, csr, (const bf16x8*)wB, b1, Wfc, bfc, h1);
    k_layer<true><<<blocks, 256, 0, stream>>>(
        h1, rowptr, csr, (const bf16x8*)(wB + 32768), b2, Wfc, bfc, d_out);
}

// Round 14
// 254.722 us; speedup vs baseline: 1.1403x; 1.0105x over previous
//
#include <hip/hip_runtime.h>
#include <cstdint>

#define NN 100000
#define CH 128
#define NT_BLK 32
#define SCAN_B 256

#define AGG_F (1u << 30)
#define PRE_F (2u << 30)
#define VAL_M ((1u << 30) - 1)

typedef __bf16 bf16x8 __attribute__((ext_vector_type(8)));
typedef __bf16 bf16x4 __attribute__((ext_vector_type(4)));
typedef float  f32x4  __attribute__((ext_vector_type(4)));

__device__ __forceinline__ float b2f(unsigned short u) {
    union { unsigned int i; float f; } v; v.i = ((unsigned int)u) << 16; return v.f;
}

// ====== fused: edge count+slot | x->bf16 | weights->fragments (independent) ======
__global__ __launch_bounds__(256) void k_count_xw(
    const int* __restrict__ dst, int* __restrict__ cnt, int* __restrict__ slot, int E,
    const float* __restrict__ x, unsigned short* __restrict__ xb,
    const float* __restrict__ W1l, const float* __restrict__ W1r,
    const float* __restrict__ W2l, const float* __restrict__ W2r,
    __bf16* __restrict__ wB, int eb, int xcb)
{
    const int b = blockIdx.x;
    const int t = threadIdx.x;
    if (b < eb) {
        const int e = b * 256 + t;
        if (e < E) slot[e] = atomicAdd(&cnt[dst[e]], 1);
        return;
    }
    if (b < eb + xcb) {
        const size_t i = ((size_t)(b - eb) * 256 + t) * 8;
        if (i < (size_t)NN * CH) {
            const float4 a = *reinterpret_cast<const float4*>(x + i);
            const float4 c = *reinterpret_cast<const float4*>(x + i + 4);
            bf16x8 o;
            o[0] = (__bf16)a.x; o[1] = (__bf16)a.y; o[2] = (__bf16)a.z; o[3] = (__bf16)a.w;
            o[4] = (__bf16)c.x; o[5] = (__bf16)c.y; o[6] = (__bf16)c.z; o[7] = (__bf16)c.w;
            *reinterpret_cast<bf16x8*>(xb + i) = o;
        }
        return;
    }
    // weight fragments: [layer][kt:8][nt:8][lane:64][8]:
    //   elem i = B[kt*32+(lane>>4)*8+i][nt*16+(lane&15)], B=[Wl;Wr] (256x128)
    const int gtid = (b - eb - xcb) * 256 + t;   // 0..8191
    const int l    = gtid >> 12;
    const int rem  = gtid & 4095;
    const int kt   = rem >> 9;
    const int nt   = (rem >> 6) & 7;
    const int lane = rem & 63;
    const float* Wl = l ? W2l : W1l;
    const float* Wr = l ? W2r : W1r;
    const int nn = nt * 16 + (lane & 15);
    const int k0 = kt * 32 + (lane >> 4) * 8;
    bf16x8 v;
#pragma unroll
    for (int i = 0; i < 8; ++i) {
        const int k = k0 + i;
        const float f = (k < CH) ? Wl[k * CH + nn] : Wr[(k - CH) * CH + nn];
        v[i] = (__bf16)f;
    }
    *reinterpret_cast<bf16x8*>(wB + (size_t)gtid * 8) = v;
}

// ====== single-pass scan, decoupled lookback (verified R13) ======
__global__ __launch_bounds__(SCAN_B) void k_scan_lb(
    const int* __restrict__ cnt, int* __restrict__ rowptr,
    unsigned* __restrict__ flagval, int n, int E)
{
    __shared__ int tmp[SCAN_B];
    __shared__ int sbase;
    const int t = threadIdx.x;
    const int c = blockIdx.x;
    const int i = c * SCAN_B + t;
    const int v = (i < n) ? cnt[i] : 0;
    tmp[t] = v;
    __syncthreads();
    for (int off = 1; off < SCAN_B; off <<= 1) {
        const int tv = (t >= off) ? tmp[t - off] : 0;
        __syncthreads();
        tmp[t] += tv;
        __syncthreads();
    }
    const int total = tmp[SCAN_B - 1];

    if (c == 0) {
        if (t == 0) {
            sbase = 0;
            __hip_atomic_store(&flagval[0], PRE_F | (unsigned)total,
                               __ATOMIC_RELEASE, __HIP_MEMORY_SCOPE_AGENT);
        }
    } else {
        if (t == 0)
            __hip_atomic_store(&flagval[c], AGG_F | (unsigned)total,
                               __ATOMIC_RELEASE, __HIP_MEMORY_SCOPE_AGENT);
        if (t < 64) {
            int base = 0;
            int j = c - 1;
            while (true) {
                const int idx = j - t;
                unsigned fv = 0;
                if (idx >= 0) {
                    do {
                        fv = __hip_atomic_load(&flagval[idx], __ATOMIC_ACQUIRE,
                                               __HIP_MEMORY_SCOPE_AGENT);
                    } while ((fv >> 30) == 0);
                }
                const unsigned long long pmask = __ballot(idx >= 0 && (fv >> 30) == 2);
                if (pmask) {
                    const int firstPre = __ffsll(pmask) - 1;
                    int contrib = (t <= firstPre && idx >= 0) ? (int)(fv & VAL_M) : 0;
#pragma unroll
                    for (int m = 1; m < 64; m <<= 1) contrib += __shfl_xor(contrib, m);
                    base += contrib;
                    break;
                }
                int contrib = (idx >= 0) ? (int)(fv & VAL_M) : 0;
#pragma unroll
                for (int m = 1; m < 64; m <<= 1) contrib += __shfl_xor(contrib, m);
                base += contrib;
                j -= 64;
            }
            if (t == 0) {
                __hip_atomic_store(&flagval[c], PRE_F | (unsigned)(base + total),
                                   __ATOMIC_RELEASE, __HIP_MEMORY_SCOPE_AGENT);
                sbase = base;
            }
        }
    }
    __syncthreads();
    const int base = sbase;
    if (i < n) rowptr[i] = tmp[t] - v + base;
    if (i == 0) rowptr[n] = E;
}

// ====== CSR fill — atomic-free ======
__global__ void k_fill(const int* __restrict__ src, const int* __restrict__ dst,
                       const int* __restrict__ slot, const int* __restrict__ rowptr,
                       int* __restrict__ csr, int E) {
    const int e = blockIdx.x * blockDim.x + threadIdx.x;
    if (e < E) csr[rowptr[dst[e]] + slot[e]] = src[e];
}

// ================= fused SAGE layer (MFMA) =================
// Phase 1 (R14): PREFETCHED gather. Per 32-lane group (4 nodes): hoist rowptr
// + skip-row loads; process node-PAIRS with all 16 csr loads then all 16 feat
// loads issued before any consume (2x in-flight vs R13's 8; compiler was
// register-starving at VGPR=40). Masks recomputed at consume (no mk regs).
// deg>8 remainder (18% of nodes) falls back to the serial masked batch.
// All array indices compile-time (no scratch). NN%NT_BLK==0: no node guards.
// Phase 2 + epilogue byte-identical to R13.
template<bool FC>
__global__ __launch_bounds__(256) void k_layer(
    const unsigned short* __restrict__ feat,
    const int* __restrict__ rowptr, const int* __restrict__ csr,
    const bf16x8* __restrict__ wfrag,
    const float* __restrict__ bias,
    const float* __restrict__ Wfc, const float* __restrict__ bfc,
    void* __restrict__ outv)
{
    __shared__ unsigned short a_lds[NT_BLK * 256];   // 16 KB
    __shared__ float red[4][16];
    char* lb = (char*)a_lds;
    const int tid = threadIdx.x;
    const int node0 = blockIdx.x * NT_BLK;
    const int g = tid >> 5;
    const int q = tid & 31;

    // ---- hoisted rowptr + skip rows (independent, overlap everything) ----
    int r0[4], r1[4];
    ushort4 sk[4];
#pragma unroll
    for (int it = 0; it < 4; ++it) {
        const int node = node0 + it * 8 + g;
        r0[it] = rowptr[node];
        r1[it] = rowptr[node + 1];
    }
#pragma unroll
    for (int it = 0; it < 4; ++it)
        sk[it] = *reinterpret_cast<const ushort4*>(
            feat + (size_t)(node0 + it * 8 + g) * CH + q * 4);

    float4 s[4];
#pragma unroll
    for (int it = 0; it < 4; ++it) s[it] = make_float4(0.f, 0.f, 0.f, 0.f);

    // ---- paired first-batch gather ----
#pragma unroll
    for (int half = 0; half < 2; ++half) {
        const int itA = half * 2, itB = itA + 1;
        const int lastA = r1[itA] - 1, lastB = r1[itB] - 1;
        int idxA[8], idxB[8];
#pragma unroll
        for (int u = 0; u < 8; ++u) {
            const int p = r0[itA] + u;
            idxA[u] = csr[p <= lastA ? p : lastA];
        }
#pragma unroll
        for (int u = 0; u < 8; ++u) {
            const int p = r0[itB] + u;
            idxB[u] = csr[p <= lastB ? p : lastB];
        }
        ushort4 uvA[8], uvB[8];
#pragma unroll
        for (int u = 0; u < 8; ++u)
            uvA[u] = *reinterpret_cast<const ushort4*>(feat + (size_t)idxA[u] * CH + q * 4);
#pragma unroll
        for (int u = 0; u < 8; ++u)
            uvB[u] = *reinterpret_cast<const ushort4*>(feat + (size_t)idxB[u] * CH + q * 4);
#pragma unroll
        for (int u = 0; u < 8; ++u) {
            const float m = (r0[itA] + u < r1[itA]) ? 1.f : 0.f;
            s[itA].x += m * b2f(uvA[u].x);
            s[itA].y += m * b2f(uvA[u].y);
            s[itA].z += m * b2f(uvA[u].z);
            s[itA].w += m * b2f(uvA[u].w);
        }
#pragma unroll
        for (int u = 0; u < 8; ++u) {
            const float m = (r0[itB] + u < r1[itB]) ? 1.f : 0.f;
            s[itB].x += m * b2f(uvB[u].x);
            s[itB].y += m * b2f(uvB[u].y);
            s[itB].z += m * b2f(uvB[u].z);
            s[itB].w += m * b2f(uvB[u].w);
        }
        // ---- deg>8 remainders (rare) ----
        for (int rr = r0[itA] + 8; rr < r1[itA]; rr += 8) {
            ushort4 uv[8];
#pragma unroll
            for (int u = 0; u < 8; ++u) {
                const int p = rr + u;
                const int id = csr[p <= lastA ? p : lastA];
                uv[u] = *reinterpret_cast<const ushort4*>(feat + (size_t)id * CH + q * 4);
            }
#pragma unroll
            for (int u = 0; u < 8; ++u) {
                const float m = (rr + u < r1[itA]) ? 1.f : 0.f;
                s[itA].x += m * b2f(uv[u].x);
                s[itA].y += m * b2f(uv[u].y);
                s[itA].z += m * b2f(uv[u].z);
                s[itA].w += m * b2f(uv[u].w);
            }
        }
        for (int rr = r0[itB] + 8; rr < r1[itB]; rr += 8) {
            ushort4 uv[8];
#pragma unroll
            for (int u = 0; u < 8; ++u) {
                const int p = rr + u;
                const int id = csr[p <= lastB ? p : lastB];
                uv[u] = *reinterpret_cast<const ushort4*>(feat + (size_t)id * CH + q * 4);
            }
#pragma unroll
            for (int u = 0; u < 8; ++u) {
                const float m = (rr + u < r1[itB]) ? 1.f : 0.f;
                s[itB].x += m * b2f(uv[u].x);
                s[itB].y += m * b2f(uv[u].y);
                s[itB].z += m * b2f(uv[u].z);
                s[itB].w += m * b2f(uv[u].w);
            }
        }
    }

    // ---- finalize: scale + swizzled LDS stores ----
#pragma unroll
    for (int it = 0; it < 4; ++it) {
        const int r = it * 8 + g;
        const int swz = (r & 7) << 4;
        const float invd = 1.0f / fmaxf((float)(r1[it] - r0[it]), 1.0f);
        bf16x4 a;
        a[0] = (__bf16)(s[it].x * invd);
        a[1] = (__bf16)(s[it].y * invd);
        a[2] = (__bf16)(s[it].z * invd);
        a[3] = (__bf16)(s[it].w * invd);
        *reinterpret_cast<bf16x4*>(lb + r * 512 + ((q * 8) ^ swz)) = a;
        *reinterpret_cast<bf16x4*>(lb + r * 512 + ((256 + q * 8) ^ swz)) =
            *reinterpret_cast<const bf16x4*>(&sk[it]);   // exact bit copy
    }
    __syncthreads();

    // ---- Phase 2: MFMA dual-GEMM (K=256 folded) — unchanged ----
    const int lane = tid & 63;
    const int w = tid >> 6;
    const int rows16 = (w >> 1) * 16;
    const int ntbase = (w & 1) * 4;
    const int row = rows16 + (lane & 15);
    const int rswz = (row & 7) << 4;
    const int abase = row * 512;
    const int asub = (lane >> 4) * 16;

    f32x4 acc[4];
#pragma unroll
    for (int nt = 0; nt < 4; ++nt) { acc[nt][0] = 0.f; acc[nt][1] = 0.f; acc[nt][2] = 0.f; acc[nt][3] = 0.f; }

#pragma unroll
    for (int kt = 0; kt < 8; ++kt) {
        const bf16x8 a = *reinterpret_cast<const bf16x8*>(lb + abase + ((kt * 64 + asub) ^ rswz));
        const bf16x8* bp = wfrag + kt * 512 + ntbase * 64 + lane;
#pragma unroll
        for (int nt = 0; nt < 4; ++nt) {
            const bf16x8 b = bp[nt * 64];
            acc[nt] = __builtin_amdgcn_mfma_f32_16x16x32_bf16(a, b, acc[nt], 0, 0, 0);
        }
    }

    const int nbase = lane & 15;
    if (!FC) {
        __bf16* out = (__bf16*)outv;
#pragma unroll
        for (int nt = 0; nt < 4; ++nt) {
            const int ch = (ntbase + nt) * 16 + nbase;
            const float bv = bias[ch];
#pragma unroll
            for (int rr = 0; rr < 4; ++rr) {
                const int node = node0 + rows16 + (lane >> 4) * 4 + rr;
                if (node < NN)
                    out[(size_t)node * CH + ch] = (__bf16)fmaxf(acc[nt][rr] + bv, 0.0f);
            }
        }
    } else {
        float* out = (float*)outv;
        float p[4] = {0.f, 0.f, 0.f, 0.f};
#pragma unroll
        for (int nt = 0; nt < 4; ++nt) {
            const int ch = (ntbase + nt) * 16 + nbase;
            const float bv = bias[ch];
            const float wf = Wfc[ch];
#pragma unroll
            for (int rr = 0; rr < 4; ++rr)
                p[rr] += fmaxf(acc[nt][rr] + bv, 0.0f) * wf;
        }
#pragma unroll
        for (int m = 1; m < 16; m <<= 1) {
#pragma unroll
            for (int rr = 0; rr < 4; ++rr) p[rr] += __shfl_xor(p[rr], m);
        }
        if (nbase == 0) {
#pragma unroll
            for (int rr = 0; rr < 4; ++rr)
                red[w][(lane >> 4) * 4 + rr] = p[rr];
        }
        __syncthreads();
        if (tid < NT_BLK) {
            const int rloc = tid;
            const float z = (rloc < 16 ? red[0][rloc] + red[1][rloc]
                                       : red[2][rloc - 16] + red[3][rloc - 16]) + bfc[0];
            const int node = node0 + rloc;
            if (node < NN) out[node] = 1.0f / (1.0f + expf(-z));
        }
    }
}

// ================= launch =================

extern "C" void kernel_launch(void* const* d_in, const int* in_sizes, int n_in,
                              void* d_out, int out_size, void* d_ws, size_t ws_size,
                              hipStream_t stream) {
    const float* x   = (const float*)d_in[0];
    const int*   ei  = (const int*)d_in[1];
    const float* W1l = (const float*)d_in[2];
    const float* W1r = (const float*)d_in[3];
    const float* b1  = (const float*)d_in[4];
    const float* W2l = (const float*)d_in[5];
    const float* W2r = (const float*)d_in[6];
    const float* b2  = (const float*)d_in[7];
    const float* Wfc = (const float*)d_in[8];
    const float* bfc = (const float*)d_in[9];

    const int E = in_sizes[1] / 2;
    const int* src = ei;
    const int* dst = ei + E;

    // ws: h1 | xb | wB | cnt[NN] flagval[512] | rowptr | slot | csr
    unsigned short* h1 = (unsigned short*)d_ws;
    unsigned short* xb = h1 + (size_t)NN * CH;
    __bf16*   wB      = (__bf16*)(xb + (size_t)NN * CH);
    int*      cnt     = (int*)(wB + 65536);
    unsigned* flagval = (unsigned*)(cnt + NN);
    int*      rowptr  = (int*)(flagval + 512);
    int*      slot    = rowptr + NN + 1;
    int*      csr     = slot + E;

    const int nb  = (NN + SCAN_B - 1) / SCAN_B;     // 391
    const int eb  = (E + 255) / 256;                // 2500
    const int xcb = (NN * CH) / 2048;               // 6250

    hipMemsetAsync(cnt, 0, (size_t)(NN + 512) * sizeof(int), stream);  // cnt + flags
    k_count_xw<<<eb + xcb + 32, 256, 0, stream>>>(dst, cnt, slot, E, x, xb,
                                                  W1l, W1r, W2l, W2r, wB, eb, xcb);
    k_scan_lb<<<nb, SCAN_B, 0, stream>>>(cnt, rowptr, flagval, NN, E);
    k_fill<<<eb, 256, 0, stream>>>(src, dst, slot, rowptr, csr, E);

    const int blocks = (NN + NT_BLK - 1) / NT_BLK;   // 3125
    k_layer<false><<<blocks, 256, 0, stream>>>(
        xb, rowptr, csr, (const bf16x8*)wB, b1, Wfc, bfc, h1);
    k_layer<true><<<blocks, 256, 0, stream>>>(
        h1, rowptr, csr, (const bf16x8*)(wB + 32768), b2, Wfc, bfc, d_out);
}